// Round 1
// 1033.424 us; speedup vs baseline: 1.1106x; 1.1106x over previous
//
#include <hip/hip_runtime.h>

#define N_NODES 100000
#define N_EDGES 800000
#define D 128
#define NBUCK 98          // dst >> 10, dst < 100000
#define CAP 10240         // per-bucket record capacity (avg 8163, max ~8600)
#define NSTRIP 3125       // N_NODES / 32 exactly
#define SMP 264           // LDS row stride in ushorts (256 data + 16B pad)

typedef __attribute__((ext_vector_type(8))) short short8;
typedef __attribute__((ext_vector_type(4))) float float4_t;
typedef unsigned short ushort_t;

__device__ __forceinline__ float b2fu(unsigned short u) {
    unsigned int v = ((unsigned int)u) << 16;
    return __builtin_bit_cast(float, v);
}
__device__ __forceinline__ unsigned short f2b(float f) {
    unsigned int u = __builtin_bit_cast(unsigned int, f);
    u = u + 0x7fffu + ((u >> 16) & 1u);   // RNE
    return (unsigned short)(u >> 16);
}
__device__ __forceinline__ void splitf(float x, unsigned short& h, unsigned short& l) {
    h = f2b(x);
    l = f2b(x - b2fu(h));
}
// split 8 consecutive f32 into hi/lo bf16 MFMA A-fragments
__device__ __forceinline__ void split8(const float* p, short8& hh, short8& ll) {
    float4 u0 = *(const float4*)p;
    float4 u1 = *(const float4*)(p + 4);
    float vv[8] = {u0.x, u0.y, u0.z, u0.w, u1.x, u1.y, u1.z, u1.w};
#pragma unroll
    for (int j = 0; j < 8; j++) {
        unsigned short h, l;
        splitf(vv[j], h, l);
        hh[j] = (short)h;
        ll[j] = (short)l;
    }
}

// ---------------- setup: zero counters + int32/int64 layout detect ----------
__global__ void setup_kernel(const unsigned int* __restrict__ w, int* __restrict__ flag,
                             int* __restrict__ bucketCount) {
    int t = threadIdx.x;
    if (t == 0) flag[0] = 0;
    for (int i = t; i < 3 * NBUCK; i += 256) bucketCount[i] = 0;
    __syncthreads();
    int any = 0;
    for (int i = t; i < 4096; i += 256)
        if (w[2 * i + 1] != 0) any = 1;   // int64 => odd words zero
    if (any) atomicOr(flag, 1);
}

__device__ __forceinline__ int ld_idx(const int* w, int f, long j) {
    return f ? w[j] : w[2 * j];
}

// ---------------- CSR build via 2-level bucket sort -------------------------
__global__ __launch_bounds__(256) void s2_bucket_kernel(const int* __restrict__ ei,
                                                        const int* __restrict__ flag,
                                                        int* __restrict__ bucketCount,
                                                        unsigned int* __restrict__ tmp) {
    __shared__ int hist[NBUCK];
    __shared__ int cnt[NBUCK];
    int t = threadIdx.x;
    int g = blockIdx.y;
    const int f = flag[0];
    const long j0 = (long)g * 2 * N_EDGES;
    if (t < NBUCK) hist[t] = 0;
    __syncthreads();
#pragma unroll
    for (int it = 0; it < 16; it++) {
        int e = blockIdx.x * 4096 + it * 256 + t;
        if (e < N_EDGES) {
            int dst = ld_idx(ei, f, j0 + N_EDGES + e);
            atomicAdd(&hist[dst >> 10], 1);
        }
    }
    __syncthreads();
    if (t < NBUCK) cnt[t] = atomicAdd(&bucketCount[g * NBUCK + t], hist[t]);
    __syncthreads();
#pragma unroll
    for (int it = 0; it < 16; it++) {
        int e = blockIdx.x * 4096 + it * 256 + t;
        if (e < N_EDGES) {
            int src = ld_idx(ei, f, j0 + e);
            int dst = ld_idx(ei, f, j0 + N_EDGES + e);
            int b = dst >> 10;
            int r = atomicAdd(&cnt[b], 1);
            if (r < CAP)
                tmp[(size_t)(g * NBUCK + b) * CAP + r] =
                    (unsigned)src | ((unsigned)(dst & 1023) << 17);
        }
    }
}

// one block per (bucket, graph); bucket base computed inline (scan folded in)
__global__ __launch_bounds__(1024) void s3_csr_kernel(const unsigned int* __restrict__ tmp,
                                                      const int* __restrict__ bucketCount,
                                                      int* __restrict__ rowptr,
                                                      int* __restrict__ col) {
    __shared__ int sm[1024];
    __shared__ int pr[1024];
    __shared__ int sbase;
    int b = blockIdx.x, g = blockIdx.y, t = threadIdx.x;
    pr[t] = 0;
    if (t < 128) sm[t] = (t < NBUCK) ? bucketCount[g * NBUCK + t] : 0;
    __syncthreads();
    if (t == 0) {
        int a = 0;
        for (int i = 0; i < b; i++) a += sm[i];
        sbase = a;
    }
    __syncthreads();
    int count = bucketCount[g * NBUCK + b];
    if (count > CAP) count = CAP;
    const unsigned int* recs = tmp + (size_t)(g * NBUCK + b) * CAP;
    for (int i = t; i < count; i += 1024) atomicAdd(&pr[recs[i] >> 17], 1);
    __syncthreads();
    int h = pr[t];
    sm[t] = h;
    __syncthreads();
    for (int off = 1; off < 1024; off <<= 1) {
        int u = (t >= off) ? sm[t - off] : 0;
        __syncthreads();
        sm[t] += u;
        __syncthreads();
    }
    int excl = sm[t] - h;
    int base = sbase;
    int node = b * 1024 + t;
    if (node < N_NODES) rowptr[g * (N_NODES + 1) + node] = base + excl;
    if (b == NBUCK - 1 && t == 0) rowptr[g * (N_NODES + 1) + N_NODES] = N_EDGES;
    __syncthreads();
    pr[t] = base + excl;
    __syncthreads();
    for (int i = t; i < count; i += 1024) {
        unsigned int rec = recs[i];
        int pos = atomicAdd(&pr[rec >> 17], 1);
        col[(size_t)g * N_EDGES + pos] = (int)(rec & 0x1FFFFu);
    }
}

// ---------------- weight pack: all 6 (graph,layer) packs in one launch ------
__global__ void packB_kernel(const float* __restrict__ Wl1, const float* __restrict__ Wr1,
                             const float* __restrict__ Wl2, const float* __restrict__ Wr2,
                             ushort_t* __restrict__ Bph, ushort_t* __restrict__ Bpl) {
    int lane = threadIdx.x;  // 64
    int tb = blockIdx.x;     // 64
    int pidx = blockIdx.y;   // 6: g*2 + layer
    int g = pidx >> 1, layer = pidx & 1;
    const float* Wl = (layer ? Wl2 : Wl1) + (size_t)g * D * D;
    const float* Wr = (layer ? Wr2 : Wr1) + (size_t)g * D * D;
    int ks = tb >> 3, nt = tb & 7;
    int n = nt * 16 + (lane & 15);
    int kb = ks * 32 + ((lane >> 4) * 8);
    short8 vh, vl;
#pragma unroll
    for (int j = 0; j < 8; j++) {
        int k = kb + j;
        float wv = (k < D) ? Wl[k * D + n] : Wr[(k - D) * D + n];
        unsigned short h, l;
        splitf(wv, h, l);
        vh[j] = (short)h;
        vl[j] = (short)l;
    }
    size_t o = ((size_t)pidx * 4096 + tb * 64 + lane) * 8;
    *(short8*)(Bph + o) = vh;
    *(short8*)(Bpl + o) = vl;
}

// ---------------- fused agg -> LDS (hi/lo split, padded) --------------------
// half-wave per node, 4 nodes per half-wave; lane l5 owns features l5*4..+4
__device__ __forceinline__ void agg_to_lds(const int* __restrict__ rp,
                                           const int* __restrict__ cle,
                                           const float* __restrict__ X,
                                           int n0, int t, ushort_t* smA) {
    int hw = t >> 5, l5 = t & 31;
#pragma unroll
    for (int k = 0; k < 4; k++) {
        int li = hw * 4 + k;
        int node = n0 + li;
        int s = rp[node], e = rp[node + 1];
        float a0 = 0.f, a1 = 0.f, a2 = 0.f, a3 = 0.f;
        for (int i = s; i < e; i++) {
            int src = cle[i];
            float4 v = *(const float4*)(X + (size_t)src * D + l5 * 4);
            a0 += v.x; a1 += v.y; a2 += v.z; a3 += v.w;
        }
        float inv = (e > s) ? 1.f / (float)(e - s) : 0.f;
        a0 *= inv; a1 *= inv; a2 *= inv; a3 *= inv;
        unsigned short h0, h1, h2, h3, l0, l1, l2, l3;
        splitf(a0, h0, l0); splitf(a1, h1, l1);
        splitf(a2, h2, l2); splitf(a3, h3, l3);
        uint2 vh = {(unsigned)h0 | ((unsigned)h1 << 16), (unsigned)h2 | ((unsigned)h3 << 16)};
        uint2 vl = {(unsigned)l0 | ((unsigned)l1 << 16), (unsigned)l2 | ((unsigned)l3 << 16)};
        *(uint2*)(smA + li * SMP + l5 * 4) = vh;
        *(uint2*)(smA + li * SMP + 128 + l5 * 4) = vl;
    }
}

// ---------------- fused split-bf16 MFMA tile: 32 rows x 32 cols per wave ----
__device__ __forceinline__ void gemm_tile(const ushort_t* smA, const float* __restrict__ Xself,
                                          int n0, const ushort_t* __restrict__ bh_base,
                                          const ushort_t* __restrict__ bl_base,
                                          int w, int lane, float4_t acc[2][2]) {
    int r0 = lane & 15, koff = (lane >> 4) * 8;
#pragma unroll
    for (int ks = 0; ks < 8; ks++) {
        int kk = (ks & 3) * 32 + koff;
        short8 a0h, a0l, a1h, a1l;
        if (ks < 4) {          // agg half: from LDS (pre-split)
            a0h = *(const short8*)(smA + r0 * SMP + kk);
            a0l = *(const short8*)(smA + r0 * SMP + 128 + kk);
            a1h = *(const short8*)(smA + (r0 + 16) * SMP + kk);
            a1l = *(const short8*)(smA + (r0 + 16) * SMP + 128 + kk);
        } else {               // self half: split f32 on the fly
            split8(Xself + (size_t)(n0 + r0) * D + kk, a0h, a0l);
            split8(Xself + (size_t)(n0 + r0 + 16) * D + kk, a1h, a1l);
        }
#pragma unroll
        for (int j = 0; j < 2; j++) {
            int nt = w * 2 + j;
            short8 wh = *(const short8*)(bh_base + ((size_t)(ks * 8 + nt) * 64 + lane) * 8);
            short8 wl = *(const short8*)(bl_base + ((size_t)(ks * 8 + nt) * 64 + lane) * 8);
            acc[0][j] = __builtin_amdgcn_mfma_f32_16x16x32_bf16(a0h, wh, acc[0][j], 0, 0, 0);
            acc[0][j] = __builtin_amdgcn_mfma_f32_16x16x32_bf16(a0l, wh, acc[0][j], 0, 0, 0);
            acc[0][j] = __builtin_amdgcn_mfma_f32_16x16x32_bf16(a0h, wl, acc[0][j], 0, 0, 0);
            acc[1][j] = __builtin_amdgcn_mfma_f32_16x16x32_bf16(a1h, wh, acc[1][j], 0, 0, 0);
            acc[1][j] = __builtin_amdgcn_mfma_f32_16x16x32_bf16(a1l, wh, acc[1][j], 0, 0, 0);
            acc[1][j] = __builtin_amdgcn_mfma_f32_16x16x32_bf16(a1h, wl, acc[1][j], 0, 0, 0);
        }
    }
}

// ---------------- layer 1: h = relu(mean(x)@Wl1 + x@Wr1 + bl1) -> f32 -------
__global__ __launch_bounds__(256) void l1_kernel(const int* __restrict__ rowptr,
                                                 const int* __restrict__ col,
                                                 const float* __restrict__ x,
                                                 const ushort_t* __restrict__ Bph,
                                                 const ushort_t* __restrict__ Bpl,
                                                 const float* __restrict__ bl1,
                                                 float* __restrict__ HF) {
    __shared__ ushort_t smA[32 * SMP];
    int g = blockIdx.y, strip = blockIdx.x;
    int t = threadIdx.x, w = t >> 6, lane = t & 63;
    int n0 = strip * 32;
    const int* rp = rowptr + (size_t)g * (N_NODES + 1);
    const int* cle = col + (size_t)g * N_EDGES;
    const float* X = x + (size_t)g * N_NODES * D;

    agg_to_lds(rp, cle, X, n0, t, smA);
    __syncthreads();

    float4_t acc[2][2];
#pragma unroll
    for (int m = 0; m < 2; m++)
#pragma unroll
        for (int j = 0; j < 2; j++) acc[m][j] = (float4_t)(0.f);
    gemm_tile(smA, X, n0, Bph + (size_t)(g * 2) * 32768, Bpl + (size_t)(g * 2) * 32768,
              w, lane, acc);

    int q = lane >> 4, c = lane & 15;
    float* H = HF + (size_t)g * N_NODES * D;
#pragma unroll
    for (int m = 0; m < 2; m++)
#pragma unroll
        for (int j = 0; j < 2; j++) {
            int clm = (w * 2 + j) * 16 + c;
            float bv = bl1[g * D + clm];
#pragma unroll
            for (int r = 0; r < 4; r++) {
                int row = n0 + m * 16 + q * 4 + r;
                H[(size_t)row * D + clm] = fmaxf(acc[m][j][r] + bv, 0.f);
            }
        }
}

// ---------------- layer 2: all 3 graphs accumulated in registers ------------
__global__ __launch_bounds__(256) void l2_kernel(const int* __restrict__ rowptr,
                                                 const int* __restrict__ col,
                                                 const float* __restrict__ HF,
                                                 const ushort_t* __restrict__ Bph,
                                                 const ushort_t* __restrict__ Bpl,
                                                 const float* __restrict__ bl2,
                                                 float* __restrict__ out) {
    __shared__ ushort_t smA[32 * SMP];
    int strip = blockIdx.x;
    int t = threadIdx.x, w = t >> 6, lane = t & 63;
    int n0 = strip * 32;
    float4_t accT[2][2];
#pragma unroll
    for (int m = 0; m < 2; m++)
#pragma unroll
        for (int j = 0; j < 2; j++) accT[m][j] = (float4_t)(0.f);

#pragma unroll 1
    for (int g = 0; g < 3; g++) {
        const int* rp = rowptr + (size_t)g * (N_NODES + 1);
        const int* cle = col + (size_t)g * N_EDGES;
        const float* H = HF + (size_t)g * N_NODES * D;

        agg_to_lds(rp, cle, H, n0, t, smA);
        __syncthreads();

        float4_t acc[2][2];
#pragma unroll
        for (int m = 0; m < 2; m++)
#pragma unroll
            for (int j = 0; j < 2; j++) acc[m][j] = (float4_t)(0.f);
        gemm_tile(smA, H, n0, Bph + (size_t)(g * 2 + 1) * 32768,
                  Bpl + (size_t)(g * 2 + 1) * 32768, w, lane, acc);

        float wgt = (g == 0) ? 1.f : 0.5f;
#pragma unroll
        for (int m = 0; m < 2; m++)
#pragma unroll
            for (int j = 0; j < 2; j++) accT[m][j] += acc[m][j] * wgt;
        __syncthreads();   // smA safe to overwrite next g
    }

    int q = lane >> 4, c = lane & 15;
#pragma unroll
    for (int m = 0; m < 2; m++)
#pragma unroll
        for (int j = 0; j < 2; j++) {
            int clm = (w * 2 + j) * 16 + c;
            float bv = bl2[clm] + 0.5f * (bl2[D + clm] + bl2[2 * D + clm]);
#pragma unroll
            for (int r = 0; r < 4; r++) {
                int row = n0 + m * 16 + q * 4 + r;
                out[(size_t)row * D + clm] = accT[m][j][r] + bv;
            }
        }
}

extern "C" void kernel_launch(void* const* d_in, const int* in_sizes, int n_in,
                              void* d_out, int out_size, void* d_ws, size_t ws_size,
                              hipStream_t stream) {
    const float* x   = (const float*)d_in[0];
    const int* ei    = (const int*)d_in[1];
    const float* Wl1 = (const float*)d_in[2];
    const float* bl1 = (const float*)d_in[3];
    const float* Wr1 = (const float*)d_in[4];
    const float* Wl2 = (const float*)d_in[5];
    const float* bl2 = (const float*)d_in[6];
    const float* Wr2 = (const float*)d_in[7];
    float* out = (float*)d_out;

    char* p = (char*)d_ws;
    auto alloc = [&](size_t bytes) -> char* {
        char* r = p;
        p += (bytes + 255) & ~(size_t)255;
        return r;
    };
    int* flag        = (int*)alloc(256);
    int* bucketCount = (int*)alloc((size_t)3 * NBUCK * 4);
    int* rowptr      = (int*)alloc((size_t)3 * (N_NODES + 1) * 4);
    int* col         = (int*)alloc((size_t)3 * N_EDGES * 4);
    ushort_t* Bph    = (ushort_t*)alloc((size_t)6 * 32768 * 2);
    ushort_t* Bpl    = (ushort_t*)alloc((size_t)6 * 32768 * 2);
    float* HF        = (float*)alloc((size_t)3 * N_NODES * D * 4);  // 153.6 MB, h (f32)
    // CSR scatter records aliased onto HF (lifetimes disjoint: s2/s3 run before l1)
    unsigned int* tmp = (unsigned int*)HF;   // 3*98*10240*4 = 12 MB < 153.6 MB
    // total ws ~= 165 MB

    setup_kernel<<<1, 256, 0, stream>>>((const unsigned int*)ei, flag, bucketCount);
    dim3 s2g((N_EDGES + 4095) / 4096, 3);
    s2_bucket_kernel<<<s2g, 256, 0, stream>>>(ei, flag, bucketCount, tmp);
    dim3 s3g(NBUCK, 3);
    s3_csr_kernel<<<s3g, 1024, 0, stream>>>(tmp, bucketCount, rowptr, col);
    packB_kernel<<<dim3(64, 6), 64, 0, stream>>>(Wl1, Wr1, Wl2, Wr2, Bph, Bpl);
    l1_kernel<<<dim3(NSTRIP, 3), 256, 0, stream>>>(rowptr, col, x, Bph, Bpl, bl1, HF);
    l2_kernel<<<NSTRIP, 256, 0, stream>>>(rowptr, col, HF, Bph, Bpl, bl2, out);
}